// Round 2
// baseline (357.889 us; speedup 1.0000x reference)
//
#include <hip/hip_runtime.h>

// MixtralRouter: x [T=16384, H=4096] f32, W [E=8, H=4096] f32
// outputs (concat, all f32): scores [T,8], weights [T,2], indices [T,2] (as float)
//
// Memory-bound: x = 268 MB streamed once -> ~43us floor @ 6.3 TB/s.
// One wave handles 4 tokens; lane i covers h = it*256 + 4*i (float4) ->
// each x load is 1KB contiguous per wave. W re-read from L2 (~500MB L2
// traffic, overlapped). No LDS, no barriers.
//
// This revision: (1) explicit 1-deep prefetch of next-iteration x loads
// (HBM ~900cy latency) so they overlap the 256 VALU cycles of FMAs;
// (2) nontemporal x loads (zero reuse; keep L2 for W) — via clang
// ext_vector_type since __builtin_nontemporal_load rejects HIP_vector_type;
// (3) __launch_bounds__(256,4) pins VGPR<=128 so 4 blocks/CU stay resident.

#define H 4096
#define E 8
#define TOK_PER_WAVE 4
#define NIT (H / 256)

typedef float fx4 __attribute__((ext_vector_type(4)));

__global__ __launch_bounds__(256, 4) void router_kernel(
    const float* __restrict__ x,
    const float* __restrict__ W,
    float* __restrict__ out,
    int T)
{
    const int tid  = blockIdx.x * blockDim.x + threadIdx.x;
    const int wave = tid >> 6;
    const int lane = tid & 63;
    const int tok0 = wave * TOK_PER_WAVE;
    if (tok0 >= T) return;

    float acc[TOK_PER_WAVE][E];
#pragma unroll
    for (int t = 0; t < TOK_PER_WAVE; ++t)
#pragma unroll
        for (int e = 0; e < E; ++e) acc[t][e] = 0.f;

    const int hbase = lane * 4;

    const float* xrow[TOK_PER_WAVE];
#pragma unroll
    for (int t = 0; t < TOK_PER_WAVE; ++t)
        xrow[t] = x + (size_t)(tok0 + t) * H + hbase;
    const float* wrow = W + hbase;

    // Prologue: load iteration 0's x fragments (nontemporal).
    fx4 xv[TOK_PER_WAVE];
#pragma unroll
    for (int t = 0; t < TOK_PER_WAVE; ++t)
        xv[t] = __builtin_nontemporal_load(
            reinterpret_cast<const fx4*>(xrow[t]));

    // Main loop: prefetch x for it+1, then FMA on it.
#pragma unroll 1
    for (int it = 0; it < NIT - 1; ++it) {
        fx4 xn[TOK_PER_WAVE];
#pragma unroll
        for (int t = 0; t < TOK_PER_WAVE; ++t)
            xn[t] = __builtin_nontemporal_load(
                reinterpret_cast<const fx4*>(xrow[t] + (it + 1) * 256));

        fx4 wv[E];
#pragma unroll
        for (int e = 0; e < E; ++e)
            wv[e] = *reinterpret_cast<const fx4*>(
                &wrow[(size_t)e * H + it * 256]);

#pragma unroll
        for (int t = 0; t < TOK_PER_WAVE; ++t)
#pragma unroll
            for (int e = 0; e < E; ++e) {
                float a = acc[t][e];
                a = fmaf(xv[t].x, wv[e].x, a);
                a = fmaf(xv[t].y, wv[e].y, a);
                a = fmaf(xv[t].z, wv[e].z, a);
                a = fmaf(xv[t].w, wv[e].w, a);
                acc[t][e] = a;
            }

#pragma unroll
        for (int t = 0; t < TOK_PER_WAVE; ++t) xv[t] = xn[t];
    }

    // Epilogue iteration (no prefetch).
    {
        const int it = NIT - 1;
        fx4 wv[E];
#pragma unroll
        for (int e = 0; e < E; ++e)
            wv[e] = *reinterpret_cast<const fx4*>(
                &wrow[(size_t)e * H + it * 256]);

#pragma unroll
        for (int t = 0; t < TOK_PER_WAVE; ++t)
#pragma unroll
            for (int e = 0; e < E; ++e) {
                float a = acc[t][e];
                a = fmaf(xv[t].x, wv[e].x, a);
                a = fmaf(xv[t].y, wv[e].y, a);
                a = fmaf(xv[t].z, wv[e].z, a);
                a = fmaf(xv[t].w, wv[e].w, a);
                acc[t][e] = a;
            }
    }

    // Full-wave butterfly reduction: every lane ends with the complete sums.
#pragma unroll
    for (int t = 0; t < TOK_PER_WAVE; ++t)
#pragma unroll
        for (int e = 0; e < E; ++e) {
            float v = acc[t][e];
            v += __shfl_xor(v, 1, 64);
            v += __shfl_xor(v, 2, 64);
            v += __shfl_xor(v, 4, 64);
            v += __shfl_xor(v, 8, 64);
            v += __shfl_xor(v, 16, 64);
            v += __shfl_xor(v, 32, 64);
            acc[t][e] = v;
        }

    // Lanes 0..3 each finalize one token.
    if (lane < TOK_PER_WAVE) {
        const int tok = tok0 + lane;

        // Extract this lane's token logits with compile-time indices.
        float l[E];
#pragma unroll
        for (int t = 0; t < TOK_PER_WAVE; ++t)
            if (lane == t) {
#pragma unroll
                for (int e = 0; e < E; ++e) l[e] = acc[t][e];
            }

        // Softmax (fp32, max-subtracted, matches jax.nn.softmax)
        float mx = l[0];
#pragma unroll
        for (int e = 1; e < E; ++e) mx = fmaxf(mx, l[e]);
        float ex[E];
        float s = 0.f;
#pragma unroll
        for (int e = 0; e < E; ++e) { ex[e] = expf(l[e] - mx); s += ex[e]; }
        const float inv = 1.f / s;
        float sc[E];
#pragma unroll
        for (int e = 0; e < E; ++e) sc[e] = ex[e] * inv;

        // scores: [T,8] at offset 0 — two float4 stores (32B aligned)
        float4 s0 = make_float4(sc[0], sc[1], sc[2], sc[3]);
        float4 s1 = make_float4(sc[4], sc[5], sc[6], sc[7]);
        *reinterpret_cast<float4*>(&out[(size_t)tok * 8])     = s0;
        *reinterpret_cast<float4*>(&out[(size_t)tok * 8 + 4]) = s1;

        // Top-2 on logits (softmax is monotone); ties -> lowest index
        // (strict >), matching jax.lax.top_k.
        int i1 = 0; float v1 = l[0];
#pragma unroll
        for (int e = 1; e < E; ++e)
            if (l[e] > v1) { v1 = l[e]; i1 = e; }
        int i2 = -1; float v2 = -3.4e38f;
#pragma unroll
        for (int e = 0; e < E; ++e)
            if (e != i1 && l[e] > v2) { v2 = l[e]; i2 = e; }

        // Renormalized top-2 weights (recomputed from logits to avoid
        // dynamic indexing into sc[] -> scratch).
        const float sA = expf(v1 - mx) * inv;
        const float sB = expf(v2 - mx) * inv;
        const float wsum = sA + sB;
        const float wA = sA / wsum;
        const float wB = sB / wsum;

        const size_t woff = (size_t)T * 8 + (size_t)tok * 2;
        *reinterpret_cast<float2*>(&out[woff]) = make_float2(wA, wB);

        const size_t ioff = (size_t)T * 8 + (size_t)T * 2 + (size_t)tok * 2;
        *reinterpret_cast<float2*>(&out[ioff]) = make_float2((float)i1, (float)i2);
    }
}

extern "C" void kernel_launch(void* const* d_in, const int* in_sizes, int n_in,
                              void* d_out, int out_size, void* d_ws, size_t ws_size,
                              hipStream_t stream) {
    const float* x = (const float*)d_in[0];
    const float* W = (const float*)d_in[1];
    float* out = (float*)d_out;

    const int T = in_sizes[0] / H;               // 16384
    const int tok_per_block = (256 / 64) * TOK_PER_WAVE;  // 16
    const int blocks = (T + tok_per_block - 1) / tok_per_block;

    router_kernel<<<blocks, 256, 0, stream>>>(x, W, out, T);
}